// Round 16
// baseline (296.990 us; speedup 1.0000x reference)
//
#include <hip/hip_runtime.h>

// Problem constants (fixed by the reference):
#define NN    40000
#define EE    640000
#define INC   128
#define HID   256
#define OUTC  10
#define GG    64
#define CAP   64        // CSR slot capacity per node (max in-degree << 64 for E/N=16)

typedef unsigned short u16;
typedef __attribute__((ext_vector_type(8))) short short8;   // 8 bf16 (4 VGPRs)
typedef __attribute__((ext_vector_type(4))) float f32x4;    // MFMA acc

__device__ __forceinline__ float bf2f(u16 h) {
    return __uint_as_float(((unsigned)h) << 16);
}
__device__ __forceinline__ u16 f2bf(float f) {   // round-to-nearest-even
    unsigned u = __float_as_uint(f);
    unsigned r = u + 0x7FFFu + ((u >> 16) & 1u);
    return (u16)(r >> 16);
}

// ---------------------------------------------------------------------------
// countfill: ONE pass over edges. rank = cnt[dst]++ ; col[dst*CAP+rank] = src.
// col is u16 (node ids < 65536). 4 edges/thread via int4 loads.
__global__ void countfill_kernel(const int* __restrict__ src, const int* __restrict__ dst,
                                 int* __restrict__ cnt, u16* __restrict__ col, int e4) {
    int i = blockIdx.x * blockDim.x + threadIdx.x;
    if (i < e4) {
        int4 d = ((const int4*)dst)[i];
        int4 s = ((const int4*)src)[i];
        int r0 = atomicAdd(&cnt[d.x], 1);
        int r1 = atomicAdd(&cnt[d.y], 1);
        int r2 = atomicAdd(&cnt[d.z], 1);
        int r3 = atomicAdd(&cnt[d.w], 1);
        if (r0 < CAP) col[(d.x << 6) + r0] = (u16)s.x;
        if (r1 < CAP) col[(d.y << 6) + r1] = (u16)s.y;
        if (r2 < CAP) col[(d.z << 6) + r2] = (u16)s.z;
        if (r3 < CAP) col[(d.w << 6) + r3] = (u16)s.w;
    }
}

// ---------------------------------------------------------------------------
// prep: three independent segments in one flat grid (all need only cnt/W/x):
//  [0, WTOT)                : weight transpose + bf16 hi/lo split
//  [WTOT, WTOT+total4)      : xs = bf16(rsqrt(cnt[row]+1) * x), 4 elems/thread
//  [WTOT+total4, ... + NN)  : dis[i] = rsqrt(cnt[i]+1)  (for agg/gemm epilogue)
#define WTOT (INC * HID + HID * HID)
__global__ void prep_kernel(const float* __restrict__ W1, u16* __restrict__ w1h,
                            u16* __restrict__ w1l,
                            const float* __restrict__ W2, u16* __restrict__ w2h,
                            u16* __restrict__ w2l,
                            const float* __restrict__ x, const int* __restrict__ cnt,
                            float* __restrict__ dis, u16* __restrict__ xs, int total4) {
    int i = blockIdx.x * blockDim.x + threadIdx.x;
    if (i < WTOT) {
        const float* W; u16 *Th, *Tl; int K, idx;
        if (i < INC * HID) { W = W1; Th = w1h; Tl = w1l; K = INC; idx = i; }
        else { W = W2; Th = w2h; Tl = w2l; K = HID; idx = i - INC * HID; }
        int k = idx >> 8;          // /256
        int n = idx & 255;
        float w = W[idx];          // idx == k*256 + n (row-major)
        u16 h = f2bf(w);
        float r = w - bf2f(h);
        Th[(size_t)n * K + k] = h;
        Tl[(size_t)n * K + k] = f2bf(r);
    } else if (i < WTOT + total4) {
        int j = i - WTOT;
        float4 v = ((const float4*)x)[j];
        int row = (j << 2) >> 7;            // /INC with INC=128
        float d = rsqrtf((float)(cnt[row] + 1));
        ushort4 o;
        o.x = f2bf(v.x * d); o.y = f2bf(v.y * d);
        o.z = f2bf(v.z * d); o.w = f2bf(v.w * d);
        ((ushort4*)xs)[j] = o;
    } else {
        int k = i - WTOT - total4;
        if (k < NN) dis[k] = rsqrtf((float)(cnt[k] + 1));
    }
}

// ---------------------------------------------------------------------------
// MFMA GEMM: C[M, 256] = A[M,K](bf16) @ (Wh+Wl)[K,256] (W stored transposed
// [256][K] bf16 hi/lo). Epilogue: v = relu(acc + bias[n]);
//  MODE 0: store bf16(dis[m]*v) to Cout           (layer 1)
//  MODE 1: accumulate v into pooled[batch[m]][n]  (layer 2 + pool phase 1
//          fused, conflict-free: per-graph masked register partials +
//          shfl_xor(16,32) qd-fold, one LDS atomic per (wave,graph,col)).
// Tile 64x128 (BM halved from 128 in R16): 40000/64 = 625 x 2 = 1250 blocks
// (~4.9/CU vs R15's 626 = 2.4/CU whose 12% occupancy left each block's
// barrier latency fully exposed — mgemm MODE1 was 52 us at 7% MFMA).
// LDS ~26 KB -> 5 blocks/CU co-resident. A re-read x2 is L3-absorbed.
// 256 threads = 4 waves; each wave 32 rows x 64 cols = 2x4 16x16x32 tiles.
#define BM 64
#define BN 128
#define BK 32
#define LDP 40   // padded LDS row length (bf16 elems): 80 B -> 2-way aliasing only
#define PGL 4    // max local graphs per 64-row tile (graphs ~625 nodes)

template<int MODE>
__global__ __launch_bounds__(256) void mgemm_kernel(
    const u16* __restrict__ A,   // [M,K] bf16
    const u16* __restrict__ Bh,  // [256,K] bf16 (W^T hi)
    const u16* __restrict__ Bl,  // [256,K] bf16 (W^T lo)
    const float* __restrict__ bias,
    const float* __restrict__ dis,
    u16* __restrict__ Cout,
    const int* __restrict__ batch, float* __restrict__ pooled,
    int M, int K)
{
    __shared__ u16 As [BM * LDP];       // 5.1 KB
    __shared__ u16 Bhs[BN * LDP];       // 10.2 KB
    __shared__ u16 Bls[BN * LDP];       // 10.2 KB
    __shared__ float ptile[MODE == 1 ? PGL * BN : 1];   // 2 KB in MODE 1 only

    const int tid  = threadIdx.x;
    const int lane = tid & 63;
    const int wave = tid >> 6;
    const int ln   = lane & 15;        // col within 16x16 tile
    const int qd   = lane >> 4;        // quad: k-unit for A/B frags, row-quad for C
    const int wm   = (wave & 1) * 32;  // wave m-offset in tile
    const int wn   = (wave >> 1) * 64; // wave n-offset in tile
    const int m0   = blockIdx.x * BM;
    const int n0   = blockIdx.y * BN;

    f32x4 acc[2][4];
#pragma unroll
    for (int i = 0; i < 2; ++i)
#pragma unroll
        for (int j = 0; j < 4; ++j) acc[i][j] = (f32x4)(0.0f);

    if (MODE == 1) {
        for (int t = tid; t < PGL * BN; t += 256) ptile[t] = 0.0f;
    }

    for (int k0 = 0; k0 < K; k0 += BK) {
        // ---- stage A (64x32) and B hi/lo (128n x 32k) into LDS ----
        // A: 64 rows x 4 k-units = 256 uint4 slots -> 1 per thread
        // B: 128 rows x 4 k-units = 512 slots -> 2 per thread each
        uint4 av, bhv[2], blv[2];
        {
            int r = tid >> 2;                  // 0..63 row
            int u = tid & 3;                   // k-unit (8 bf16)
            int grow = m0 + r;
            av = make_uint4(0u, 0u, 0u, 0u);
            if (grow < M)
                av = *(const uint4*)(A + (size_t)grow * K + k0 + u * 8);
        }
#pragma unroll
        for (int i = 0; i < 2; ++i) {
            int flat = tid + i * 256;          // 0..511
            int r = flat >> 2;                 // 0..127 row
            int u = flat & 3;
            bhv[i] = *(const uint4*)(Bh + (size_t)(n0 + r) * K + k0 + u * 8);
            blv[i] = *(const uint4*)(Bl + (size_t)(n0 + r) * K + k0 + u * 8);
        }
        __syncthreads();   // previous chunk's frag reads complete
        {
            int r = tid >> 2;
            int u = tid & 3;
            *(uint4*)(As + r * LDP + u * 8) = av;
        }
#pragma unroll
        for (int i = 0; i < 2; ++i) {
            int flat = tid + i * 256;
            int r = flat >> 2;
            int u = flat & 3;
            *(uint4*)(Bhs + r * LDP + u * 8) = bhv[i];
            *(uint4*)(Bls + r * LDP + u * 8) = blv[i];
        }
        __syncthreads();

        // ---- fragments + MFMA ----
        short8 af[2], bfh[4], bfl[4];
#pragma unroll
        for (int t = 0; t < 2; ++t)
            af[t]  = *(const short8*)(As  + (wm + t * 16 + ln) * LDP + qd * 8);
#pragma unroll
        for (int t = 0; t < 4; ++t) {
            bfh[t] = *(const short8*)(Bhs + (wn + t * 16 + ln) * LDP + qd * 8);
            bfl[t] = *(const short8*)(Bls + (wn + t * 16 + ln) * LDP + qd * 8);
        }
#pragma unroll
        for (int ti = 0; ti < 2; ++ti)
#pragma unroll
            for (int tj = 0; tj < 4; ++tj) {
                acc[ti][tj] = __builtin_amdgcn_mfma_f32_16x16x32_bf16(
                    af[ti], bfh[tj], acc[ti][tj], 0, 0, 0);
                acc[ti][tj] = __builtin_amdgcn_mfma_f32_16x16x32_bf16(
                    af[ti], bfl[tj], acc[ti][tj], 0, 0, 0);
            }
    }

    // ---- epilogue: C layout col=lane&15, row=qd*4+reg ----
    float bcol[4];
#pragma unroll
    for (int tj = 0; tj < 4; ++tj) bcol[tj] = bias[n0 + wn + tj * 16 + ln];

    if (MODE == 0) {
#pragma unroll
        for (int ti = 0; ti < 2; ++ti) {
#pragma unroll
            for (int r = 0; r < 4; ++r) {
                int row = m0 + wm + ti * 16 + qd * 4 + r;
                if (row < M) {
                    float dm = dis[row];
                    u16* crow = Cout + (size_t)row * HID;
#pragma unroll
                    for (int tj = 0; tj < 4; ++tj) {
                        float v = fmaxf(acc[ti][tj][r] + bcol[tj], 0.0f);
                        crow[n0 + wn + tj * 16 + ln] = f2bf(v * dm);
                    }
                }
            }
        }
    } else {
        // cache graph ids of this thread's 8 rows
        int bg[8];
#pragma unroll
        for (int ti = 0; ti < 2; ++ti)
#pragma unroll
            for (int r = 0; r < 4; ++r) {
                int row = m0 + wm + ti * 16 + qd * 4 + r;
                bg[ti * 4 + r] = (row < M) ? batch[row] : -1;
            }
        const int g_lo = batch[m0];
        const int g_hi = batch[min(m0 + BM, M) - 1];
        for (int g = g_lo; g <= g_hi; ++g) {
            float cs[4] = {0.0f, 0.0f, 0.0f, 0.0f};
#pragma unroll
            for (int ti = 0; ti < 2; ++ti)
#pragma unroll
                for (int r = 0; r < 4; ++r)
                    if (bg[ti * 4 + r] == g) {
#pragma unroll
                        for (int tj = 0; tj < 4; ++tj)
                            cs[tj] += fmaxf(acc[ti][tj][r] + bcol[tj], 0.0f);
                    }
            // fold the 4 qd lanes holding the same column (lane bits 16, 32)
#pragma unroll
            for (int tj = 0; tj < 4; ++tj) {
                cs[tj] += __shfl_xor(cs[tj], 16);
                cs[tj] += __shfl_xor(cs[tj], 32);
            }
            if (qd == 0) {
                int gl = g - g_lo;
#pragma unroll
                for (int tj = 0; tj < 4; ++tj) {
                    int c = wn + tj * 16 + ln;
                    if (gl < PGL) atomicAdd(&ptile[gl * BN + c], cs[tj]);
                    else atomicAdd(&pooled[(size_t)g * HID + n0 + c], cs[tj]);
                }
            }
        }
        __syncthreads();
        const int g0 = batch[m0];
        for (int t = tid; t < PGL * BN; t += 256) {
            float v = ptile[t];
            if (v != 0.0f) {
                int gl = t / BN, c = t % BN;
                atomicAdd(&pooled[(size_t)(g0 + gl) * HID + n0 + c], v);
            }
        }
    }
}

// ---------------------------------------------------------------------------
// Aggregation, wave-per-node, unrolled for memory-level parallelism.
// out[n,:] = bf16(dis[n] * (hs[n,:] + sum_{src in in(n)} hs[src,:]))
// Lanes form G groups of L=F/8; each lane loads uint4 = 8 bf16 (16 B).
// Indices come from the CAP-slotted CSR: col[n*CAP + i], i < cnt[n].
// PROVEN CONFIG — 48.5 us (R7/R9/R11/R12). Failed experiments, do not retry:
//   R8:  UF x2 (32 items in flight) -> allocator serializes, occ halves, 62 us
//   R10: 2 waves/node -> occupancy unchanged, VALU overhead x2, 52 us
//   R13: 4-phase src-range partition for L2 locality -> FETCH unchanged
//        (waves don't stay synchronized), VALU 34->56%, 63.5 us
// ~48.5 us = 348 MB logical / 7.2 TB/s effective is this pattern's floor.
template<int F>
__global__ __launch_bounds__(256) void agg_kernel(
    const u16* __restrict__ hs, const int* __restrict__ cnt,
    const u16* __restrict__ col, const float* __restrict__ dis,
    u16* __restrict__ out, int n_nodes)
{
    constexpr int L  = F / 8;                   // lanes per item (16 or 32)
    constexpr int G  = 64 / L;                  // items per batch (4 or 2)
    constexpr int UF = 16 / G;                  // batches per iteration
    const int lane = threadIdx.x & 63;
    const int n    = (blockIdx.x * blockDim.x + threadIdx.x) >> 6;  // wave id
    if (n >= n_nodes) return;
    const int li = lane % L;
    const int gi = lane / L;

    const int base0 = n << 6;                   // n*CAP
    const int total = 1 + cnt[n];               // self + edges

    float acc[8];
#pragma unroll
    for (int i = 0; i < 8; ++i) acc[i] = 0.0f;

    for (int base = 0; base < total; base += G * UF) {
        int  idxs[UF];
        bool valid[UF];
        // phase 1: independent col-index loads (broadcast within group)
#pragma unroll
        for (int u = 0; u < UF; ++u) {
            int it = base + u * G + gi;
            valid[u] = (it < total);
            idxs[u] = 0;
            if (valid[u]) idxs[u] = (it == 0) ? n : (int)col[base0 + it - 1];
        }
        // phase 2: independent row gathers (UF outstanding loads)
        uint4 w[UF];
#pragma unroll
        for (int u = 0; u < UF; ++u)
            if (valid[u])
                w[u] = *(const uint4*)(hs + (size_t)idxs[u] * F + li * 8);
        // phase 3: accumulate
#pragma unroll
        for (int u = 0; u < UF; ++u)
            if (valid[u]) {
                unsigned uu[4] = {w[u].x, w[u].y, w[u].z, w[u].w};
#pragma unroll
                for (int q = 0; q < 4; ++q) {
                    acc[2 * q]     += __uint_as_float(uu[q] << 16);
                    acc[2 * q + 1] += __uint_as_float(uu[q] & 0xFFFF0000u);
                }
            }
    }

    // combine the G partial groups (lane strides L..32)
#pragma unroll
    for (int off = 32; off >= L; off >>= 1)
#pragma unroll
        for (int i = 0; i < 8; ++i)
            acc[i] += __shfl_xor(acc[i], off);

    if (gi == 0) {
        float d = dis[n];
        unsigned r[4];
#pragma unroll
        for (int q = 0; q < 4; ++q) {
            unsigned l16 = (unsigned)f2bf(acc[2 * q] * d);
            unsigned h16 = (unsigned)f2bf(acc[2 * q + 1] * d);
            r[q] = l16 | (h16 << 16);
        }
        *(uint4*)(out + (size_t)n * F + li * 8) = make_uint4(r[0], r[1], r[2], r[3]);
    }
}

// ---------------------------------------------------------------------------
// Pool finalize: divide pooled sums by counts (binary search on sorted batch)
// + final linear.  (Pool phase 1 lives in mgemm<1>'s epilogue.)
__global__ __launch_bounds__(256) void pool_finalize_kernel(
    const float* __restrict__ pooled, const int* __restrict__ batch,
    const float* __restrict__ Wlin, const float* __restrict__ blin,
    float* __restrict__ out, int n_nodes)
{
    const int g = blockIdx.x;
    const int j = threadIdx.x;
    int lo = 0, hi = n_nodes;
    while (lo < hi) { int mid = (lo + hi) >> 1; if (batch[mid] < g) lo = mid + 1; else hi = mid; }
    const int start = lo;
    lo = start; hi = n_nodes;
    while (lo < hi) { int mid = (lo + hi) >> 1; if (batch[mid] < g + 1) lo = mid + 1; else hi = mid; }
    const int cnt = lo - start;

    float pv = pooled[(size_t)g * HID + j] / fmaxf((float)cnt, 1.0f);

    __shared__ float pl[HID];
    pl[j] = pv;
    __syncthreads();
    if (j < OUTC) {
        float o = blin[j];
        for (int k = 0; k < HID; ++k) o = fmaf(pl[k], Wlin[k * OUTC + j], o);
        out[g * OUTC + j] = o;
    }
}

// ---------------------------------------------------------------------------
extern "C" void kernel_launch(void* const* d_in, const int* in_sizes, int n_in,
                              void* d_out, int out_size, void* d_ws, size_t ws_size,
                              hipStream_t stream) {
    const float* x     = (const float*)d_in[0];
    const int*   ei    = (const int*)  d_in[1];   // [2, E]: row0 src, row1 dst
    const int*   batch = (const int*)  d_in[2];
    const float* W1    = (const float*)d_in[3];
    const float* b1    = (const float*)d_in[4];
    const float* W2    = (const float*)d_in[5];
    const float* b2    = (const float*)d_in[6];
    const float* Wlin  = (const float*)d_in[7];
    const float* blin  = (const float*)d_in[8];
    float* out = (float*)d_out;

    const int* src = ei;
    const int* dst = ei + EE;

    // workspace layout. [pooled|cnt] contiguous -> zeroed by one hipMemsetAsync.
    char* p = (char*)d_ws;
    u16*   xs  = (u16*)p;   p += (size_t)NN * INC * sizeof(u16);    // 10.24 MB
    u16*   xab = (u16*)p;   p += (size_t)NN * INC * sizeof(u16);    // 10.24 MB
    u16*   h1s = (u16*)p;   p += (size_t)NN * HID * sizeof(u16);    // 20.48 MB
    u16*   a2b = (u16*)p;   p += (size_t)NN * HID * sizeof(u16);    // 20.48 MB
    u16*   w1h = (u16*)p;   p += (size_t)HID * INC * sizeof(u16);
    u16*   w1l = (u16*)p;   p += (size_t)HID * INC * sizeof(u16);
    u16*   w2h = (u16*)p;   p += (size_t)HID * HID * sizeof(u16);
    u16*   w2l = (u16*)p;   p += (size_t)HID * HID * sizeof(u16);
    float* dis = (float*)p; p += (size_t)NN * sizeof(float);
    char* zbase = p;                                         // memset region:
    float* pooled = (float*)p; p += (size_t)GG * HID * sizeof(float); //  pooled
    int* cnt    = (int*)p;  p += (size_t)NN * sizeof(int);            //  cnt
    size_t zbytes = (size_t)(p - zbase);
    u16* col    = (u16*)p;  p += (size_t)NN * CAP * sizeof(u16);      // 5.12 MB
    (void)ws_size; (void)n_in; (void)in_sizes; (void)out_size;

    const int TB = 256;
    const int e4   = EE / 4;                  // EE divisible by 4
    const int nb_e4 = (e4 + TB - 1) / TB;

    // graph structure in ONE edge pass (rebuilt every call; ws re-poisoned)
    hipMemsetAsync(zbase, 0, zbytes, stream);
    countfill_kernel<<<nb_e4, TB, 0, stream>>>(src, dst, cnt, col, e4);

    // fused weight split + xs quantize + dis
    const int total4 = NN * INC / 4;
    const int prep_threads = WTOT + total4 + NN;
    prep_kernel<<<(prep_threads + TB - 1) / TB, TB, 0, stream>>>(
        W1, w1h, w1l, W2, w2h, w2l, x, cnt, dis, xs, total4);

    dim3 ggrid((NN + BM - 1) / BM, HID / BN);   // 625 x 2 = 1250 blocks
    const int agg_blocks = (NN * 64 + TB - 1) / TB;   // one wave per node

    // layer 1: xab = bf16(dis .* (xs self + gather)); h1s = bf16(dis .* relu(xab@W1 + b1))
    agg_kernel<INC><<<agg_blocks, TB, 0, stream>>>(xs, cnt, col, dis, xab, NN);
    mgemm_kernel<0><<<ggrid, 256, 0, stream>>>(xab, w1h, w1l, b1, dis, h1s,
                                               batch, pooled, NN, INC);

    // layer 2: a2b = bf16(dis .* (h1s self + gather));
    // gemm2 fuses relu(a2b@W2 + b2) with pool phase 1 (conflict-free reduction)
    agg_kernel<HID><<<agg_blocks, TB, 0, stream>>>(h1s, cnt, col, dis, a2b, NN);
    mgemm_kernel<1><<<ggrid, 256, 0, stream>>>(a2b, w2h, w2l, b2, dis, (u16*)nullptr,
                                               batch, pooled, NN, HID);

    // pool finalize (divide by counts) + linear
    pool_finalize_kernel<<<GG, 256, 0, stream>>>(pooled, batch, Wlin, blin, out, NN);
}

// Round 17
// 273.794 us; speedup vs baseline: 1.0847x; 1.0847x over previous
//
#include <hip/hip_runtime.h>

// Problem constants (fixed by the reference):
#define NN    40000
#define EE    640000
#define INC   128
#define HID   256
#define OUTC  10
#define GG    64
#define CAP   64        // CSR slot capacity per node (max in-degree << 64 for E/N=16)

typedef unsigned short u16;
typedef __attribute__((ext_vector_type(8))) short short8;   // 8 bf16 (4 VGPRs)
typedef __attribute__((ext_vector_type(4))) float f32x4;    // MFMA acc

__device__ __forceinline__ float bf2f(u16 h) {
    return __uint_as_float(((unsigned)h) << 16);
}
__device__ __forceinline__ u16 f2bf(float f) {   // round-to-nearest-even
    unsigned u = __float_as_uint(f);
    unsigned r = u + 0x7FFFu + ((u >> 16) & 1u);
    return (u16)(r >> 16);
}

// ---------------------------------------------------------------------------
// countfill: ONE pass over edges. rank = cnt[dst]++ ; col[dst*CAP+rank] = src.
// col is u16 (node ids < 65536). 4 edges/thread via int4 loads.
__global__ void countfill_kernel(const int* __restrict__ src, const int* __restrict__ dst,
                                 int* __restrict__ cnt, u16* __restrict__ col, int e4) {
    int i = blockIdx.x * blockDim.x + threadIdx.x;
    if (i < e4) {
        int4 d = ((const int4*)dst)[i];
        int4 s = ((const int4*)src)[i];
        int r0 = atomicAdd(&cnt[d.x], 1);
        int r1 = atomicAdd(&cnt[d.y], 1);
        int r2 = atomicAdd(&cnt[d.z], 1);
        int r3 = atomicAdd(&cnt[d.w], 1);
        if (r0 < CAP) col[(d.x << 6) + r0] = (u16)s.x;
        if (r1 < CAP) col[(d.y << 6) + r1] = (u16)s.y;
        if (r2 < CAP) col[(d.z << 6) + r2] = (u16)s.z;
        if (r3 < CAP) col[(d.w << 6) + r3] = (u16)s.w;
    }
}

// ---------------------------------------------------------------------------
// prep: three independent segments in one flat grid (all need only cnt/W/x):
//  [0, WTOT)                : weight transpose + bf16 hi/lo split
//  [WTOT, WTOT+total4)      : xs = bf16(rsqrt(cnt[row]+1) * x), 4 elems/thread
//  [WTOT+total4, ... + NN)  : dis[i] = rsqrt(cnt[i]+1)  (for agg/gemm epilogue)
#define WTOT (INC * HID + HID * HID)
__global__ void prep_kernel(const float* __restrict__ W1, u16* __restrict__ w1h,
                            u16* __restrict__ w1l,
                            const float* __restrict__ W2, u16* __restrict__ w2h,
                            u16* __restrict__ w2l,
                            const float* __restrict__ x, const int* __restrict__ cnt,
                            float* __restrict__ dis, u16* __restrict__ xs, int total4) {
    int i = blockIdx.x * blockDim.x + threadIdx.x;
    if (i < WTOT) {
        const float* W; u16 *Th, *Tl; int K, idx;
        if (i < INC * HID) { W = W1; Th = w1h; Tl = w1l; K = INC; idx = i; }
        else { W = W2; Th = w2h; Tl = w2l; K = HID; idx = i - INC * HID; }
        int k = idx >> 8;          // /256
        int n = idx & 255;
        float w = W[idx];          // idx == k*256 + n (row-major)
        u16 h = f2bf(w);
        float r = w - bf2f(h);
        Th[(size_t)n * K + k] = h;
        Tl[(size_t)n * K + k] = f2bf(r);
    } else if (i < WTOT + total4) {
        int j = i - WTOT;
        float4 v = ((const float4*)x)[j];
        int row = (j << 2) >> 7;            // /INC with INC=128
        float d = rsqrtf((float)(cnt[row] + 1));
        ushort4 o;
        o.x = f2bf(v.x * d); o.y = f2bf(v.y * d);
        o.z = f2bf(v.z * d); o.w = f2bf(v.w * d);
        ((ushort4*)xs)[j] = o;
    } else {
        int k = i - WTOT - total4;
        if (k < NN) dis[k] = rsqrtf((float)(cnt[k] + 1));
    }
}

// ---------------------------------------------------------------------------
// MFMA GEMM: C[M, 256] = A[M,K](bf16) @ (Wh+Wl)[K,256] (W stored transposed
// [256][K] bf16 hi/lo). Epilogue: v = relu(acc + bias[n]);
//  MODE 0: store bf16(dis[m]*v) to Cout           (layer 1)
//  MODE 1: accumulate v into pooled[batch[m]][n]  (layer 2 + pool phase 1
//          fused, conflict-free: per-graph masked register partials +
//          shfl_xor(16,32) qd-fold, one LDS atomic per (wave,graph,col)).
// TILE: 128x128 (PROVEN — R15, 277 us total). R16's BM=64 regressed to 61 us:
// occupancy rose 12->35% but B-staging bytes + barriers doubled — per-block
// compute:staging ratio is the binding factor, NOT occupancy. Do not shrink BM.
// K-loop is SOFTWARE-PIPELINED (R17): chunk k+1's global loads issue before
// chunk k's MFMAs, hiding ~500cyc load latency behind compute instead of
// stalling the next staging step at vmcnt(0).
// 256 threads = 4 waves, each wave 4x4 16x16x32 tiles.
#define BM 128
#define BN 128
#define BK 32
#define LDP 40   // padded LDS row length (bf16 elems): 80 B -> 2-way aliasing only
#define PGL 8    // max local graphs per 128-row tile (avg graph = 625 nodes)

template<int MODE>
__global__ __launch_bounds__(256) void mgemm_kernel(
    const u16* __restrict__ A,   // [M,K] bf16
    const u16* __restrict__ Bh,  // [256,K] bf16 (W^T hi)
    const u16* __restrict__ Bl,  // [256,K] bf16 (W^T lo)
    const float* __restrict__ bias,
    const float* __restrict__ dis,
    u16* __restrict__ Cout,
    const int* __restrict__ batch, float* __restrict__ pooled,
    int M, int K)
{
    __shared__ u16 As [BM * LDP];
    __shared__ u16 Bhs[BN * LDP];
    __shared__ u16 Bls[BN * LDP];
    __shared__ float ptile[MODE == 1 ? PGL * BN : 1];   // 4 KB in MODE 1 only

    const int tid  = threadIdx.x;
    const int lane = tid & 63;
    const int wave = tid >> 6;
    const int ln   = lane & 15;        // col within 16x16 tile
    const int qd   = lane >> 4;        // quad: k-unit for A/B frags, row-quad for C
    const int wm   = (wave & 1) * 64;  // wave m-offset in tile
    const int wn   = (wave >> 1) * 64; // wave n-offset in tile
    const int m0   = blockIdx.x * BM;
    const int n0   = blockIdx.y * BN;

    f32x4 acc[4][4];
#pragma unroll
    for (int i = 0; i < 4; ++i)
#pragma unroll
        for (int j = 0; j < 4; ++j) acc[i][j] = (f32x4)(0.0f);

    if (MODE == 1) {
        for (int t = tid; t < PGL * BN; t += 256) ptile[t] = 0.0f;
    }

    // staging indices (fixed per thread)
    const int sr0 = tid >> 2,        su0 = tid & 3;          // slot 0: row 0..63
    const int sr1 = (tid + 256) >> 2, su1 = tid & 3;         // slot 1: row 64..127

    // ---- preload chunk 0 ----
    uint4 av[2], bhv[2], blv[2];
    {
        int g0 = m0 + sr0, g1 = m0 + sr1;
        av[0] = (g0 < M) ? *(const uint4*)(A + (size_t)g0 * K + su0 * 8)
                         : make_uint4(0u, 0u, 0u, 0u);
        av[1] = (g1 < M) ? *(const uint4*)(A + (size_t)g1 * K + su1 * 8)
                         : make_uint4(0u, 0u, 0u, 0u);
        bhv[0] = *(const uint4*)(Bh + (size_t)(n0 + sr0) * K + su0 * 8);
        bhv[1] = *(const uint4*)(Bh + (size_t)(n0 + sr1) * K + su1 * 8);
        blv[0] = *(const uint4*)(Bl + (size_t)(n0 + sr0) * K + su0 * 8);
        blv[1] = *(const uint4*)(Bl + (size_t)(n0 + sr1) * K + su1 * 8);
    }

    for (int k0 = 0; k0 < K; k0 += BK) {
        __syncthreads();   // previous chunk's frag reads complete
        *(uint4*)(As  + sr0 * LDP + su0 * 8) = av[0];
        *(uint4*)(As  + sr1 * LDP + su1 * 8) = av[1];
        *(uint4*)(Bhs + sr0 * LDP + su0 * 8) = bhv[0];
        *(uint4*)(Bhs + sr1 * LDP + su1 * 8) = bhv[1];
        *(uint4*)(Bls + sr0 * LDP + su0 * 8) = blv[0];
        *(uint4*)(Bls + sr1 * LDP + su1 * 8) = blv[1];
        __syncthreads();

        // ---- prefetch chunk k0+BK (issues before MFMAs; latency hidden) ----
        if (k0 + BK < K) {
            int kb = k0 + BK;
            int g0 = m0 + sr0, g1 = m0 + sr1;
            av[0] = (g0 < M) ? *(const uint4*)(A + (size_t)g0 * K + kb + su0 * 8)
                             : make_uint4(0u, 0u, 0u, 0u);
            av[1] = (g1 < M) ? *(const uint4*)(A + (size_t)g1 * K + kb + su1 * 8)
                             : make_uint4(0u, 0u, 0u, 0u);
            bhv[0] = *(const uint4*)(Bh + (size_t)(n0 + sr0) * K + kb + su0 * 8);
            bhv[1] = *(const uint4*)(Bh + (size_t)(n0 + sr1) * K + kb + su1 * 8);
            blv[0] = *(const uint4*)(Bl + (size_t)(n0 + sr0) * K + kb + su0 * 8);
            blv[1] = *(const uint4*)(Bl + (size_t)(n0 + sr1) * K + kb + su1 * 8);
        }

        // ---- fragments + MFMA ----
        short8 af[4], bfh[4], bfl[4];
#pragma unroll
        for (int t = 0; t < 4; ++t) {
            af[t]  = *(const short8*)(As  + (wm + t * 16 + ln) * LDP + qd * 8);
            bfh[t] = *(const short8*)(Bhs + (wn + t * 16 + ln) * LDP + qd * 8);
            bfl[t] = *(const short8*)(Bls + (wn + t * 16 + ln) * LDP + qd * 8);
        }
#pragma unroll
        for (int ti = 0; ti < 4; ++ti)
#pragma unroll
            for (int tj = 0; tj < 4; ++tj) {
                acc[ti][tj] = __builtin_amdgcn_mfma_f32_16x16x32_bf16(
                    af[ti], bfh[tj], acc[ti][tj], 0, 0, 0);
                acc[ti][tj] = __builtin_amdgcn_mfma_f32_16x16x32_bf16(
                    af[ti], bfl[tj], acc[ti][tj], 0, 0, 0);
            }
    }

    // ---- epilogue: C layout col=lane&15, row=qd*4+reg ----
    float bcol[4];
#pragma unroll
    for (int tj = 0; tj < 4; ++tj) bcol[tj] = bias[n0 + wn + tj * 16 + ln];

    if (MODE == 0) {
#pragma unroll
        for (int ti = 0; ti < 4; ++ti) {
#pragma unroll
            for (int r = 0; r < 4; ++r) {
                int row = m0 + wm + ti * 16 + qd * 4 + r;
                if (row < M) {
                    float dm = dis[row];
                    u16* crow = Cout + (size_t)row * HID;
#pragma unroll
                    for (int tj = 0; tj < 4; ++tj) {
                        float v = fmaxf(acc[ti][tj][r] + bcol[tj], 0.0f);
                        crow[n0 + wn + tj * 16 + ln] = f2bf(v * dm);
                    }
                }
            }
        }
    } else {
        // cache graph ids of this thread's 16 rows
        int bg[16];
#pragma unroll
        for (int ti = 0; ti < 4; ++ti)
#pragma unroll
            for (int r = 0; r < 4; ++r) {
                int row = m0 + wm + ti * 16 + qd * 4 + r;
                bg[ti * 4 + r] = (row < M) ? batch[row] : -1;
            }
        const int g_lo = batch[m0];
        const int g_hi = batch[min(m0 + BM, M) - 1];
        for (int g = g_lo; g <= g_hi; ++g) {
            float cs[4] = {0.0f, 0.0f, 0.0f, 0.0f};
#pragma unroll
            for (int ti = 0; ti < 4; ++ti)
#pragma unroll
                for (int r = 0; r < 4; ++r)
                    if (bg[ti * 4 + r] == g) {
#pragma unroll
                        for (int tj = 0; tj < 4; ++tj)
                            cs[tj] += fmaxf(acc[ti][tj][r] + bcol[tj], 0.0f);
                    }
            // fold the 4 qd lanes holding the same column (lane bits 16, 32)
#pragma unroll
            for (int tj = 0; tj < 4; ++tj) {
                cs[tj] += __shfl_xor(cs[tj], 16);
                cs[tj] += __shfl_xor(cs[tj], 32);
            }
            if (qd == 0) {
                int gl = g - g_lo;
#pragma unroll
                for (int tj = 0; tj < 4; ++tj) {
                    int c = wn + tj * 16 + ln;
                    if (gl < PGL) atomicAdd(&ptile[gl * BN + c], cs[tj]);
                    else atomicAdd(&pooled[(size_t)g * HID + n0 + c], cs[tj]);
                }
            }
        }
        __syncthreads();
        const int g0 = batch[m0];
        for (int t = tid; t < PGL * BN; t += 256) {
            float v = ptile[t];
            if (v != 0.0f) {
                int gl = t / BN, c = t % BN;
                atomicAdd(&pooled[(size_t)(g0 + gl) * HID + n0 + c], v);
            }
        }
    }
}

// ---------------------------------------------------------------------------
// Aggregation, wave-per-node, unrolled for memory-level parallelism.
// out[n,:] = bf16(dis[n] * (hs[n,:] + sum_{src in in(n)} hs[src,:]))
// Lanes form G groups of L=F/8; each lane loads uint4 = 8 bf16 (16 B).
// Indices come from the CAP-slotted CSR: col[n*CAP + i], i < cnt[n].
// PROVEN CONFIG — 48.5 us (R7/R9/R11/R12). Failed experiments, do not retry:
//   R8:  UF x2 (32 items in flight) -> allocator serializes, occ halves, 62 us
//   R10: 2 waves/node -> occupancy unchanged, VALU overhead x2, 52 us
//   R13: 4-phase src-range partition for L2 locality -> FETCH unchanged
//        (waves don't stay synchronized), VALU 34->56%, 63.5 us
// ~48.5 us = 348 MB logical / 7.2 TB/s effective is this pattern's floor.
template<int F>
__global__ __launch_bounds__(256) void agg_kernel(
    const u16* __restrict__ hs, const int* __restrict__ cnt,
    const u16* __restrict__ col, const float* __restrict__ dis,
    u16* __restrict__ out, int n_nodes)
{
    constexpr int L  = F / 8;                   // lanes per item (16 or 32)
    constexpr int G  = 64 / L;                  // items per batch (4 or 2)
    constexpr int UF = 16 / G;                  // batches per iteration
    const int lane = threadIdx.x & 63;
    const int n    = (blockIdx.x * blockDim.x + threadIdx.x) >> 6;  // wave id
    if (n >= n_nodes) return;
    const int li = lane % L;
    const int gi = lane / L;

    const int base0 = n << 6;                   // n*CAP
    const int total = 1 + cnt[n];               // self + edges

    float acc[8];
#pragma unroll
    for (int i = 0; i < 8; ++i) acc[i] = 0.0f;

    for (int base = 0; base < total; base += G * UF) {
        int  idxs[UF];
        bool valid[UF];
        // phase 1: independent col-index loads (broadcast within group)
#pragma unroll
        for (int u = 0; u < UF; ++u) {
            int it = base + u * G + gi;
            valid[u] = (it < total);
            idxs[u] = 0;
            if (valid[u]) idxs[u] = (it == 0) ? n : (int)col[base0 + it - 1];
        }
        // phase 2: independent row gathers (UF outstanding loads)
        uint4 w[UF];
#pragma unroll
        for (int u = 0; u < UF; ++u)
            if (valid[u])
                w[u] = *(const uint4*)(hs + (size_t)idxs[u] * F + li * 8);
        // phase 3: accumulate
#pragma unroll
        for (int u = 0; u < UF; ++u)
            if (valid[u]) {
                unsigned uu[4] = {w[u].x, w[u].y, w[u].z, w[u].w};
#pragma unroll
                for (int q = 0; q < 4; ++q) {
                    acc[2 * q]     += __uint_as_float(uu[q] << 16);
                    acc[2 * q + 1] += __uint_as_float(uu[q] & 0xFFFF0000u);
                }
            }
    }

    // combine the G partial groups (lane strides L..32)
#pragma unroll
    for (int off = 32; off >= L; off >>= 1)
#pragma unroll
        for (int i = 0; i < 8; ++i)
            acc[i] += __shfl_xor(acc[i], off);

    if (gi == 0) {
        float d = dis[n];
        unsigned r[4];
#pragma unroll
        for (int q = 0; q < 4; ++q) {
            unsigned l16 = (unsigned)f2bf(acc[2 * q] * d);
            unsigned h16 = (unsigned)f2bf(acc[2 * q + 1] * d);
            r[q] = l16 | (h16 << 16);
        }
        *(uint4*)(out + (size_t)n * F + li * 8) = make_uint4(r[0], r[1], r[2], r[3]);
    }
}

// ---------------------------------------------------------------------------
// Pool finalize: divide pooled sums by counts (binary search on sorted batch)
// + final linear.  (Pool phase 1 lives in mgemm<1>'s epilogue.)
__global__ __launch_bounds__(256) void pool_finalize_kernel(
    const float* __restrict__ pooled, const int* __restrict__ batch,
    const float* __restrict__ Wlin, const float* __restrict__ blin,
    float* __restrict__ out, int n_nodes)
{
    const int g = blockIdx.x;
    const int j = threadIdx.x;
    int lo = 0, hi = n_nodes;
    while (lo < hi) { int mid = (lo + hi) >> 1; if (batch[mid] < g) lo = mid + 1; else hi = mid; }
    const int start = lo;
    lo = start; hi = n_nodes;
    while (lo < hi) { int mid = (lo + hi) >> 1; if (batch[mid] < g + 1) lo = mid + 1; else hi = mid; }
    const int cnt = lo - start;

    float pv = pooled[(size_t)g * HID + j] / fmaxf((float)cnt, 1.0f);

    __shared__ float pl[HID];
    pl[j] = pv;
    __syncthreads();
    if (j < OUTC) {
        float o = blin[j];
        for (int k = 0; k < HID; ++k) o = fmaf(pl[k], Wlin[k * OUTC + j], o);
        out[g * OUTC + j] = o;
    }
}

// ---------------------------------------------------------------------------
extern "C" void kernel_launch(void* const* d_in, const int* in_sizes, int n_in,
                              void* d_out, int out_size, void* d_ws, size_t ws_size,
                              hipStream_t stream) {
    const float* x     = (const float*)d_in[0];
    const int*   ei    = (const int*)  d_in[1];   // [2, E]: row0 src, row1 dst
    const int*   batch = (const int*)  d_in[2];
    const float* W1    = (const float*)d_in[3];
    const float* b1    = (const float*)d_in[4];
    const float* W2    = (const float*)d_in[5];
    const float* b2    = (const float*)d_in[6];
    const float* Wlin  = (const float*)d_in[7];
    const float* blin  = (const float*)d_in[8];
    float* out = (float*)d_out;

    const int* src = ei;
    const int* dst = ei + EE;

    // workspace layout. [pooled|cnt] contiguous -> zeroed by one hipMemsetAsync.
    char* p = (char*)d_ws;
    u16*   xs  = (u16*)p;   p += (size_t)NN * INC * sizeof(u16);    // 10.24 MB
    u16*   xab = (u16*)p;   p += (size_t)NN * INC * sizeof(u16);    // 10.24 MB
    u16*   h1s = (u16*)p;   p += (size_t)NN * HID * sizeof(u16);    // 20.48 MB
    u16*   a2b = (u16*)p;   p += (size_t)NN * HID * sizeof(u16);    // 20.48 MB
    u16*   w1h = (u16*)p;   p += (size_t)HID * INC * sizeof(u16);
    u16*   w1l = (u16*)p;   p += (size_t)HID * INC * sizeof(u16);
    u16*   w2h = (u16*)p;   p += (size_t)HID * HID * sizeof(u16);
    u16*   w2l = (u16*)p;   p += (size_t)HID * HID * sizeof(u16);
    float* dis = (float*)p; p += (size_t)NN * sizeof(float);
    char* zbase = p;                                         // memset region:
    float* pooled = (float*)p; p += (size_t)GG * HID * sizeof(float); //  pooled
    int* cnt    = (int*)p;  p += (size_t)NN * sizeof(int);            //  cnt
    size_t zbytes = (size_t)(p - zbase);
    u16* col    = (u16*)p;  p += (size_t)NN * CAP * sizeof(u16);      // 5.12 MB
    (void)ws_size; (void)n_in; (void)in_sizes; (void)out_size;

    const int TB = 256;
    const int e4   = EE / 4;                  // EE divisible by 4
    const int nb_e4 = (e4 + TB - 1) / TB;

    // graph structure in ONE edge pass (rebuilt every call; ws re-poisoned)
    hipMemsetAsync(zbase, 0, zbytes, stream);
    countfill_kernel<<<nb_e4, TB, 0, stream>>>(src, dst, cnt, col, e4);

    // fused weight split + xs quantize + dis
    const int total4 = NN * INC / 4;
    const int prep_threads = WTOT + total4 + NN;
    prep_kernel<<<(prep_threads + TB - 1) / TB, TB, 0, stream>>>(
        W1, w1h, w1l, W2, w2h, w2l, x, cnt, dis, xs, total4);

    dim3 ggrid((NN + BM - 1) / BM, HID / BN);   // 313 x 2 blocks
    const int agg_blocks = (NN * 64 + TB - 1) / TB;   // one wave per node

    // layer 1: xab = bf16(dis .* (xs self + gather)); h1s = bf16(dis .* relu(xab@W1 + b1))
    agg_kernel<INC><<<agg_blocks, TB, 0, stream>>>(xs, cnt, col, dis, xab, NN);
    mgemm_kernel<0><<<ggrid, 256, 0, stream>>>(xab, w1h, w1l, b1, dis, h1s,
                                               batch, pooled, NN, INC);

    // layer 2: a2b = bf16(dis .* (h1s self + gather));
    // gemm2 fuses relu(a2b@W2 + b2) with pool phase 1 (conflict-free reduction)
    agg_kernel<HID><<<agg_blocks, TB, 0, stream>>>(h1s, cnt, col, dis, a2b, NN);
    mgemm_kernel<1><<<ggrid, 256, 0, stream>>>(a2b, w2h, w2l, b2, dis, (u16*)nullptr,
                                               batch, pooled, NN, HID);

    // pool finalize (divide by counts) + linear
    pool_finalize_kernel<<<GG, 256, 0, stream>>>(pooled, batch, Wlin, blin, out, NN);
}

// Round 18
// 267.643 us; speedup vs baseline: 1.1096x; 1.0230x over previous
//
#include <hip/hip_runtime.h>

// Problem constants (fixed by the reference):
#define NN    40000
#define EE    640000
#define INC   128
#define HID   256
#define OUTC  10
#define GG    64
#define CAP   64        // CSR slot capacity per node (max in-degree << 64 for E/N=16)

typedef unsigned short u16;
typedef __attribute__((ext_vector_type(8))) short short8;   // 8 bf16 (4 VGPRs)
typedef __attribute__((ext_vector_type(4))) float f32x4;    // MFMA acc

__device__ __forceinline__ float bf2f(u16 h) {
    return __uint_as_float(((unsigned)h) << 16);
}
__device__ __forceinline__ u16 f2bf(float f) {   // round-to-nearest-even
    unsigned u = __float_as_uint(f);
    unsigned r = u + 0x7FFFu + ((u >> 16) & 1u);
    return (u16)(r >> 16);
}

// ---------------------------------------------------------------------------
// build: ONE kernel, three independent segments (R18 — merges countfill+prep;
// the old prep waited on countfill only because xs/dis consumed cnt. xq is now
// quantized WITHOUT the dis scale; consumers compute rsqrt(cnt+1) on the fly):
//  [0, e4)              : edge pass — rank = cnt[dst]++ ; col[dst*CAP+rank]=src
//  [e4, e4+WTOT)        : weight transpose + bf16 hi/lo split
//  [e4+WTOT, +total4)   : xq = bf16(x), 4 elems/thread
#define WTOT (INC * HID + HID * HID)
__global__ void build_kernel(const int* __restrict__ src, const int* __restrict__ dst,
                             int* __restrict__ cnt, u16* __restrict__ col, int e4,
                             const float* __restrict__ W1, u16* __restrict__ w1h,
                             u16* __restrict__ w1l,
                             const float* __restrict__ W2, u16* __restrict__ w2h,
                             u16* __restrict__ w2l,
                             const float* __restrict__ x, u16* __restrict__ xq,
                             int total4) {
    int i = blockIdx.x * blockDim.x + threadIdx.x;
    if (i < e4) {
        int4 d = ((const int4*)dst)[i];
        int4 s = ((const int4*)src)[i];
        int r0 = atomicAdd(&cnt[d.x], 1);
        int r1 = atomicAdd(&cnt[d.y], 1);
        int r2 = atomicAdd(&cnt[d.z], 1);
        int r3 = atomicAdd(&cnt[d.w], 1);
        if (r0 < CAP) col[(d.x << 6) + r0] = (u16)s.x;
        if (r1 < CAP) col[(d.y << 6) + r1] = (u16)s.y;
        if (r2 < CAP) col[(d.z << 6) + r2] = (u16)s.z;
        if (r3 < CAP) col[(d.w << 6) + r3] = (u16)s.w;
    } else if (i < e4 + WTOT) {
        int idx = i - e4;
        const float* W; u16 *Th, *Tl; int K;
        if (idx < INC * HID) { W = W1; Th = w1h; Tl = w1l; K = INC; }
        else { W = W2; Th = w2h; Tl = w2l; K = HID; idx -= INC * HID; }
        int k = idx >> 8;          // /256
        int n = idx & 255;
        float w = W[idx];          // idx == k*256 + n (row-major)
        u16 h = f2bf(w);
        float r = w - bf2f(h);
        Th[(size_t)n * K + k] = h;
        Tl[(size_t)n * K + k] = f2bf(r);
    } else {
        int j = i - e4 - WTOT;
        if (j < total4) {
            float4 v = ((const float4*)x)[j];
            ushort4 o;
            o.x = f2bf(v.x); o.y = f2bf(v.y);
            o.z = f2bf(v.z); o.w = f2bf(v.w);
            ((ushort4*)xq)[j] = o;
        }
    }
}

// ---------------------------------------------------------------------------
// MFMA GEMM: C[M, 256] = A[M,K](bf16) @ (Wh+Wl)[K,256] (W stored transposed
// [256][K] bf16 hi/lo). Epilogue: v = relu(acc + bias[n]);
//  MODE 0: store bf16(rsqrt(cnt[m]+1)*v) to Cout  (layer 1)
//  MODE 1: accumulate v into pooled[batch[m]][n]  (layer 2 + pool phase 1
//          fused, conflict-free: per-graph masked register partials +
//          shfl_xor(16,32) qd-fold, one LDS atomic per (wave,graph,col)).
// TILE: 128x128 (PROVEN — R15/R17). R16's BM=64 regressed (occupancy rose
// 12->35% but B-staging + barriers doubled — compute:staging ratio binds,
// not occupancy). K-loop SOFTWARE-PIPELINED (R17, 297->274): chunk k+1's
// global loads issue before chunk k's MFMAs.
// 256 threads = 4 waves, each wave 4x4 16x16x32 tiles.
#define BM 128
#define BN 128
#define BK 32
#define LDP 40   // padded LDS row length (bf16 elems): 80 B -> 2-way aliasing only
#define PGL 8    // max local graphs per 128-row tile (avg graph = 625 nodes)

template<int MODE>
__global__ __launch_bounds__(256) void mgemm_kernel(
    const u16* __restrict__ A,   // [M,K] bf16
    const u16* __restrict__ Bh,  // [256,K] bf16 (W^T hi)
    const u16* __restrict__ Bl,  // [256,K] bf16 (W^T lo)
    const float* __restrict__ bias,
    const int* __restrict__ cnt,
    u16* __restrict__ Cout,
    const int* __restrict__ batch, float* __restrict__ pooled,
    int M, int K)
{
    __shared__ u16 As [BM * LDP];
    __shared__ u16 Bhs[BN * LDP];
    __shared__ u16 Bls[BN * LDP];
    __shared__ float ptile[MODE == 1 ? PGL * BN : 1];   // 4 KB in MODE 1 only

    const int tid  = threadIdx.x;
    const int lane = tid & 63;
    const int wave = tid >> 6;
    const int ln   = lane & 15;        // col within 16x16 tile
    const int qd   = lane >> 4;        // quad: k-unit for A/B frags, row-quad for C
    const int wm   = (wave & 1) * 64;  // wave m-offset in tile
    const int wn   = (wave >> 1) * 64; // wave n-offset in tile
    const int m0   = blockIdx.x * BM;
    const int n0   = blockIdx.y * BN;

    f32x4 acc[4][4];
#pragma unroll
    for (int i = 0; i < 4; ++i)
#pragma unroll
        for (int j = 0; j < 4; ++j) acc[i][j] = (f32x4)(0.0f);

    if (MODE == 1) {
        for (int t = tid; t < PGL * BN; t += 256) ptile[t] = 0.0f;
    }

    // staging indices (fixed per thread)
    const int sr0 = tid >> 2,        su0 = tid & 3;          // slot 0: row 0..63
    const int sr1 = (tid + 256) >> 2, su1 = tid & 3;         // slot 1: row 64..127

    // ---- preload chunk 0 ----
    uint4 av[2], bhv[2], blv[2];
    {
        int g0 = m0 + sr0, g1 = m0 + sr1;
        av[0] = (g0 < M) ? *(const uint4*)(A + (size_t)g0 * K + su0 * 8)
                         : make_uint4(0u, 0u, 0u, 0u);
        av[1] = (g1 < M) ? *(const uint4*)(A + (size_t)g1 * K + su1 * 8)
                         : make_uint4(0u, 0u, 0u, 0u);
        bhv[0] = *(const uint4*)(Bh + (size_t)(n0 + sr0) * K + su0 * 8);
        bhv[1] = *(const uint4*)(Bh + (size_t)(n0 + sr1) * K + su1 * 8);
        blv[0] = *(const uint4*)(Bl + (size_t)(n0 + sr0) * K + su0 * 8);
        blv[1] = *(const uint4*)(Bl + (size_t)(n0 + sr1) * K + su1 * 8);
    }

    for (int k0 = 0; k0 < K; k0 += BK) {
        __syncthreads();   // previous chunk's frag reads complete
        *(uint4*)(As  + sr0 * LDP + su0 * 8) = av[0];
        *(uint4*)(As  + sr1 * LDP + su1 * 8) = av[1];
        *(uint4*)(Bhs + sr0 * LDP + su0 * 8) = bhv[0];
        *(uint4*)(Bhs + sr1 * LDP + su1 * 8) = bhv[1];
        *(uint4*)(Bls + sr0 * LDP + su0 * 8) = blv[0];
        *(uint4*)(Bls + sr1 * LDP + su1 * 8) = blv[1];
        __syncthreads();

        // ---- prefetch chunk k0+BK (issues before MFMAs; latency hidden) ----
        if (k0 + BK < K) {
            int kb = k0 + BK;
            int g0 = m0 + sr0, g1 = m0 + sr1;
            av[0] = (g0 < M) ? *(const uint4*)(A + (size_t)g0 * K + kb + su0 * 8)
                             : make_uint4(0u, 0u, 0u, 0u);
            av[1] = (g1 < M) ? *(const uint4*)(A + (size_t)g1 * K + kb + su1 * 8)
                             : make_uint4(0u, 0u, 0u, 0u);
            bhv[0] = *(const uint4*)(Bh + (size_t)(n0 + sr0) * K + kb + su0 * 8);
            bhv[1] = *(const uint4*)(Bh + (size_t)(n0 + sr1) * K + kb + su1 * 8);
            blv[0] = *(const uint4*)(Bl + (size_t)(n0 + sr0) * K + kb + su0 * 8);
            blv[1] = *(const uint4*)(Bl + (size_t)(n0 + sr1) * K + kb + su1 * 8);
        }

        // ---- fragments + MFMA ----
        short8 af[4], bfh[4], bfl[4];
#pragma unroll
        for (int t = 0; t < 4; ++t) {
            af[t]  = *(const short8*)(As  + (wm + t * 16 + ln) * LDP + qd * 8);
            bfh[t] = *(const short8*)(Bhs + (wn + t * 16 + ln) * LDP + qd * 8);
            bfl[t] = *(const short8*)(Bls + (wn + t * 16 + ln) * LDP + qd * 8);
        }
#pragma unroll
        for (int ti = 0; ti < 4; ++ti)
#pragma unroll
            for (int tj = 0; tj < 4; ++tj) {
                acc[ti][tj] = __builtin_amdgcn_mfma_f32_16x16x32_bf16(
                    af[ti], bfh[tj], acc[ti][tj], 0, 0, 0);
                acc[ti][tj] = __builtin_amdgcn_mfma_f32_16x16x32_bf16(
                    af[ti], bfl[tj], acc[ti][tj], 0, 0, 0);
            }
    }

    // ---- epilogue: C layout col=lane&15, row=qd*4+reg ----
    float bcol[4];
#pragma unroll
    for (int tj = 0; tj < 4; ++tj) bcol[tj] = bias[n0 + wn + tj * 16 + ln];

    if (MODE == 0) {
#pragma unroll
        for (int ti = 0; ti < 4; ++ti) {
#pragma unroll
            for (int r = 0; r < 4; ++r) {
                int row = m0 + wm + ti * 16 + qd * 4 + r;
                if (row < M) {
                    float dm = rsqrtf((float)(cnt[row] + 1));
                    u16* crow = Cout + (size_t)row * HID;
#pragma unroll
                    for (int tj = 0; tj < 4; ++tj) {
                        float v = fmaxf(acc[ti][tj][r] + bcol[tj], 0.0f);
                        crow[n0 + wn + tj * 16 + ln] = f2bf(v * dm);
                    }
                }
            }
        }
    } else {
        // cache graph ids of this thread's 16 rows
        int bg[16];
#pragma unroll
        for (int ti = 0; ti < 4; ++ti)
#pragma unroll
            for (int r = 0; r < 4; ++r) {
                int row = m0 + wm + ti * 16 + qd * 4 + r;
                bg[ti * 4 + r] = (row < M) ? batch[row] : -1;
            }
        const int g_lo = batch[m0];
        const int g_hi = batch[min(m0 + BM, M) - 1];
        for (int g = g_lo; g <= g_hi; ++g) {
            float cs[4] = {0.0f, 0.0f, 0.0f, 0.0f};
#pragma unroll
            for (int ti = 0; ti < 4; ++ti)
#pragma unroll
                for (int r = 0; r < 4; ++r)
                    if (bg[ti * 4 + r] == g) {
#pragma unroll
                        for (int tj = 0; tj < 4; ++tj)
                            cs[tj] += fmaxf(acc[ti][tj][r] + bcol[tj], 0.0f);
                    }
            // fold the 4 qd lanes holding the same column (lane bits 16, 32)
#pragma unroll
            for (int tj = 0; tj < 4; ++tj) {
                cs[tj] += __shfl_xor(cs[tj], 16);
                cs[tj] += __shfl_xor(cs[tj], 32);
            }
            if (qd == 0) {
                int gl = g - g_lo;
#pragma unroll
                for (int tj = 0; tj < 4; ++tj) {
                    int c = wn + tj * 16 + ln;
                    if (gl < PGL) atomicAdd(&ptile[gl * BN + c], cs[tj]);
                    else atomicAdd(&pooled[(size_t)g * HID + n0 + c], cs[tj]);
                }
            }
        }
        __syncthreads();
        const int g0 = batch[m0];
        for (int t = tid; t < PGL * BN; t += 256) {
            float v = ptile[t];
            if (v != 0.0f) {
                int gl = t / BN, c = t % BN;
                atomicAdd(&pooled[(size_t)(g0 + gl) * HID + n0 + c], v);
            }
        }
    }
}

// ---------------------------------------------------------------------------
// Aggregation, wave-per-node, unrolled for memory-level parallelism.
// PERDIS=true  (layer 1): out[n] = bf16(d_n * sum_items d_idx * xq[idx])
//   — per-item rsqrt(cnt[idx]+1) applied at gather (replaces the old
//   pre-scaled xs array; removes prep's dependency on countfill).
// PERDIS=false (layer 2): out[n] = bf16(d_n * sum_items hs[idx]) (hs already
//   dis-scaled by mgemm<0>'s epilogue).
// Lanes form G groups of L=F/8; each lane loads uint4 = 8 bf16 (16 B).
// Indices come from the CAP-slotted CSR: col[n*CAP + i], i < cnt[n].
// PROVEN CONFIG — 48.5 us (R7/R9/R11/R12/R17). Failed experiments, do not retry:
//   R8:  UF x2 (32 items in flight) -> allocator serializes, occ halves, 62 us
//   R10: 2 waves/node -> occupancy unchanged, VALU overhead x2, 52 us
//   R13: 4-phase src-range partition for L2 locality -> FETCH unchanged
//        (waves don't stay synchronized), VALU 34->56%, 63.5 us
// ~48.5 us = 348 MB logical / 7.2 TB/s effective is this pattern's floor.
template<int F, bool PERDIS>
__global__ __launch_bounds__(256) void agg_kernel(
    const u16* __restrict__ hs, const int* __restrict__ cnt,
    const u16* __restrict__ col, u16* __restrict__ out, int n_nodes)
{
    constexpr int L  = F / 8;                   // lanes per item (16 or 32)
    constexpr int G  = 64 / L;                  // items per batch (4 or 2)
    constexpr int UF = 16 / G;                  // batches per iteration
    const int lane = threadIdx.x & 63;
    const int n    = (blockIdx.x * blockDim.x + threadIdx.x) >> 6;  // wave id
    if (n >= n_nodes) return;
    const int li = lane % L;
    const int gi = lane / L;

    const int base0 = n << 6;                   // n*CAP
    const int total = 1 + cnt[n];               // self + edges

    float acc[8];
#pragma unroll
    for (int i = 0; i < 8; ++i) acc[i] = 0.0f;

    for (int base = 0; base < total; base += G * UF) {
        int  idxs[UF];
        bool valid[UF];
        // phase 1: independent col-index loads (broadcast within group)
#pragma unroll
        for (int u = 0; u < UF; ++u) {
            int it = base + u * G + gi;
            valid[u] = (it < total);
            idxs[u] = 0;
            if (valid[u]) idxs[u] = (it == 0) ? n : (int)col[base0 + it - 1];
        }
        // phase 2: independent row gathers (+ cnt gathers for PERDIS)
        uint4 w[UF];
        int   cv[UF];
#pragma unroll
        for (int u = 0; u < UF; ++u)
            if (valid[u]) {
                w[u] = *(const uint4*)(hs + (size_t)idxs[u] * F + li * 8);
                if (PERDIS) cv[u] = cnt[idxs[u]];
            }
        // phase 3: accumulate
#pragma unroll
        for (int u = 0; u < UF; ++u)
            if (valid[u]) {
                float d = PERDIS ? rsqrtf((float)(cv[u] + 1)) : 1.0f;
                unsigned uu[4] = {w[u].x, w[u].y, w[u].z, w[u].w};
#pragma unroll
                for (int q = 0; q < 4; ++q) {
                    if (PERDIS) {
                        acc[2 * q]     = fmaf(d, __uint_as_float(uu[q] << 16), acc[2 * q]);
                        acc[2 * q + 1] = fmaf(d, __uint_as_float(uu[q] & 0xFFFF0000u), acc[2 * q + 1]);
                    } else {
                        acc[2 * q]     += __uint_as_float(uu[q] << 16);
                        acc[2 * q + 1] += __uint_as_float(uu[q] & 0xFFFF0000u);
                    }
                }
            }
    }

    // combine the G partial groups (lane strides L..32)
#pragma unroll
    for (int off = 32; off >= L; off >>= 1)
#pragma unroll
        for (int i = 0; i < 8; ++i)
            acc[i] += __shfl_xor(acc[i], off);

    if (gi == 0) {
        float d = rsqrtf((float)total);         // total == cnt[n]+1
        unsigned r[4];
#pragma unroll
        for (int q = 0; q < 4; ++q) {
            unsigned l16 = (unsigned)f2bf(acc[2 * q] * d);
            unsigned h16 = (unsigned)f2bf(acc[2 * q + 1] * d);
            r[q] = l16 | (h16 << 16);
        }
        *(uint4*)(out + (size_t)n * F + li * 8) = make_uint4(r[0], r[1], r[2], r[3]);
    }
}

// ---------------------------------------------------------------------------
// Pool finalize: divide pooled sums by counts (binary search on sorted batch)
// + final linear.  (Pool phase 1 lives in mgemm<1>'s epilogue.)
__global__ __launch_bounds__(256) void pool_finalize_kernel(
    const float* __restrict__ pooled, const int* __restrict__ batch,
    const float* __restrict__ Wlin, const float* __restrict__ blin,
    float* __restrict__ out, int n_nodes)
{
    const int g = blockIdx.x;
    const int j = threadIdx.x;
    int lo = 0, hi = n_nodes;
    while (lo < hi) { int mid = (lo + hi) >> 1; if (batch[mid] < g) lo = mid + 1; else hi = mid; }
    const int start = lo;
    lo = start; hi = n_nodes;
    while (lo < hi) { int mid = (lo + hi) >> 1; if (batch[mid] < g + 1) lo = mid + 1; else hi = mid; }
    const int cnt = lo - start;

    float pv = pooled[(size_t)g * HID + j] / fmaxf((float)cnt, 1.0f);

    __shared__ float pl[HID];
    pl[j] = pv;
    __syncthreads();
    if (j < OUTC) {
        float o = blin[j];
        for (int k = 0; k < HID; ++k) o = fmaf(pl[k], Wlin[k * OUTC + j], o);
        out[g * OUTC + j] = o;
    }
}

// ---------------------------------------------------------------------------
extern "C" void kernel_launch(void* const* d_in, const int* in_sizes, int n_in,
                              void* d_out, int out_size, void* d_ws, size_t ws_size,
                              hipStream_t stream) {
    const float* x     = (const float*)d_in[0];
    const int*   ei    = (const int*)  d_in[1];   // [2, E]: row0 src, row1 dst
    const int*   batch = (const int*)  d_in[2];
    const float* W1    = (const float*)d_in[3];
    const float* b1    = (const float*)d_in[4];
    const float* W2    = (const float*)d_in[5];
    const float* b2    = (const float*)d_in[6];
    const float* Wlin  = (const float*)d_in[7];
    const float* blin  = (const float*)d_in[8];
    float* out = (float*)d_out;

    const int* src = ei;
    const int* dst = ei + EE;

    // workspace layout. [pooled|cnt] contiguous -> zeroed by one hipMemsetAsync.
    char* p = (char*)d_ws;
    u16*   xq  = (u16*)p;   p += (size_t)NN * INC * sizeof(u16);    // 10.24 MB
    u16*   xab = (u16*)p;   p += (size_t)NN * INC * sizeof(u16);    // 10.24 MB
    u16*   h1s = (u16*)p;   p += (size_t)NN * HID * sizeof(u16);    // 20.48 MB
    u16*   a2b = (u16*)p;   p += (size_t)NN * HID * sizeof(u16);    // 20.48 MB
    u16*   w1h = (u16*)p;   p += (size_t)HID * INC * sizeof(u16);
    u16*   w1l = (u16*)p;   p += (size_t)HID * INC * sizeof(u16);
    u16*   w2h = (u16*)p;   p += (size_t)HID * HID * sizeof(u16);
    u16*   w2l = (u16*)p;   p += (size_t)HID * HID * sizeof(u16);
    char* zbase = p;                                         // memset region:
    float* pooled = (float*)p; p += (size_t)GG * HID * sizeof(float); //  pooled
    int* cnt    = (int*)p;  p += (size_t)NN * sizeof(int);            //  cnt
    size_t zbytes = (size_t)(p - zbase);
    u16* col    = (u16*)p;  p += (size_t)NN * CAP * sizeof(u16);      // 5.12 MB
    (void)ws_size; (void)n_in; (void)in_sizes; (void)out_size;

    const int TB = 256;
    const int e4     = EE / 4;                  // EE divisible by 4
    const int total4 = NN * INC / 4;
    const int build_threads = e4 + WTOT + total4;
    const int nb_build = (build_threads + TB - 1) / TB;

    // ONE fused structure+quantize pass (rebuilt every call; ws re-poisoned)
    hipMemsetAsync(zbase, 0, zbytes, stream);
    build_kernel<<<nb_build, TB, 0, stream>>>(src, dst, cnt, col, e4,
                                              W1, w1h, w1l, W2, w2h, w2l,
                                              x, xq, total4);

    dim3 ggrid((NN + BM - 1) / BM, HID / BN);   // 313 x 2 blocks
    const int agg_blocks = (NN * 64 + TB - 1) / TB;   // one wave per node

    // layer 1: xab = bf16(d_n .* (sum d_idx*xq)); h1s = bf16(d_m .* relu(xab@W1 + b1))
    agg_kernel<INC, true><<<agg_blocks, TB, 0, stream>>>(xq, cnt, col, xab, NN);
    mgemm_kernel<0><<<ggrid, 256, 0, stream>>>(xab, w1h, w1l, b1, cnt, h1s,
                                               batch, pooled, NN, INC);

    // layer 2: a2b = bf16(d_n .* (h1s self + gather));
    // gemm2 fuses relu(a2b@W2 + b2) with pool phase 1 (conflict-free reduction)
    agg_kernel<HID, false><<<agg_blocks, TB, 0, stream>>>(h1s, cnt, col, a2b, NN);
    mgemm_kernel<1><<<ggrid, 256, 0, stream>>>(a2b, w2h, w2l, b2, cnt, (u16*)nullptr,
                                               batch, pooled, NN, HID);

    // pool finalize (divide by counts) + linear
    pool_finalize_kernel<<<GG, 256, 0, stream>>>(pooled, batch, Wlin, blin, out, NN);
}